// Round 6
// baseline (611.812 us; speedup 1.0000x reference)
//
#include <hip/hip_runtime.h>
#include <hip/hip_cooperative_groups.h>

namespace cg = cooperative_groups;

// OctreeDWConvBn: out[n,c] = BN_c( sum_k data[neigh[n,k],c] * weight[k,c] )
// N=131072, C=192, K=27. fp32 in/out; gathered operand staged as bf16.
// R6: single cooperative kernel, 3 phases with grid.sync() between:
//   P1 cvt (fp32->bf16 stage + zero stats) | P2 conv+stats (R4 body) |
//   P3 BN finalize+apply. Conv phase is pinned at the ~3.3 TB/s fabric
//   ceiling (R1/R2/R4 all land there); this round eliminates everything else.

static constexpr int NN = 131072;   // nodes
static constexpr int CC = 192;      // channels
static constexpr int KK = 27;       // stencil taps
static constexpr int NB = 32;       // nodes per conv chunk
static constexpr float BN_EPS = 1e-5f;

__device__ __forceinline__ unsigned short f2bf_rne(float x) {
    unsigned u = __float_as_uint(x);
    return (unsigned short)((u + 0x7FFFu + ((u >> 16) & 1u)) >> 16);
}

// ---------------------------------------------------------------------------
// The whole pipeline in one cooperative dispatch. Block = 192 threads.
// ---------------------------------------------------------------------------
__global__ __launch_bounds__(192, 8) void fused_all(
    const float* __restrict__ data,              // [NN, CC] fp32
    const int*   __restrict__ neigh,             // [NN, KK]
    const float* __restrict__ weight,            // [KK, CC]
    const float* __restrict__ gamma,             // [CC]
    const float* __restrict__ beta,              // [CC]
    unsigned short* __restrict__ data_bf,        // ws: [NN, CC] bf16 bits
    unsigned short* __restrict__ conv_bf,        // ws: [NN, CC] bf16 bits
    float* __restrict__ stats,                   // ws: [2*CC] sum|sumsq
    float* __restrict__ out)                     // [NN, CC] fp32
{
    cg::grid_group grid = cg::this_grid();
    __shared__ float lds_w[KK * CC];             // 20736 B

    const int t = threadIdx.x;

    // Stage depthwise weights in LDS (used by phase 2).
#pragma unroll
    for (int k = 0; k < KK; ++k) lds_w[k * CC + t] = weight[k * CC + t];

    // ---- Phase 1: fp32 -> bf16 staging (grid-stride, float4 granular) ----
    if (blockIdx.x == 0) { stats[t] = 0.f; stats[CC + t] = 0.f; }
    {
        const int total4 = NN * CC / 4;          // 6291456
        for (int i = blockIdx.x * 192 + t; i < total4; i += gridDim.x * 192) {
            const float4 v = reinterpret_cast<const float4*>(data)[i];
            ushort4 o;
            o.x = f2bf_rne(v.x); o.y = f2bf_rne(v.y);
            o.z = f2bf_rne(v.z); o.w = f2bf_rne(v.w);
            reinterpret_cast<ushort4*>(data_bf)[i] = o;
        }
    }
    grid.sync();

    // ---- Phase 2: depthwise conv + stats (R4 body, grid-stride chunks) ----
    {
        float s = 0.f, ss = 0.f;
        for (int chunk = blockIdx.x; chunk < NN / NB; chunk += gridDim.x) {
            const int base = chunk * NB;
            for (int n = 0; n < NB; ++n) {
                const int node = base + n;              // block-uniform
                const int* nrow = neigh + node * KK;    // uniform -> s_load

                unsigned short r[KK];                   // 27 loads in flight
#pragma unroll
                for (int k = 0; k < KK; ++k)
                    r[k] = data_bf[(size_t)nrow[k] * CC + t];

                float acc = 0.f;
#pragma unroll
                for (int k = 0; k < KK; ++k)
                    acc = fmaf(__uint_as_float((unsigned)r[k] << 16),
                               lds_w[k * CC + t], acc);

                conv_bf[(size_t)node * CC + t] = f2bf_rne(acc);
                s  += acc;
                ss += acc * acc;
            }
        }
        atomicAdd(&stats[t],      s);    // one atomic pair per block
        atomicAdd(&stats[CC + t], ss);
    }
    grid.sync();

    // ---- Phase 3: BN finalize (per-thread) + normalize ----
    {
        const int g  = t / 48;           // node subgroup 0..3
        const int q  = t - g * 48;       // fixed channel quad 0..47
        const int cb = q * 4;
        const float inv_n = 1.0f / (float)NN;

        float4 sc, bi;
        {
            const float m0 = stats[cb + 0] * inv_n, m1 = stats[cb + 1] * inv_n;
            const float m2 = stats[cb + 2] * inv_n, m3 = stats[cb + 3] * inv_n;
            const float v0 = stats[CC + cb + 0] * inv_n - m0 * m0;
            const float v1 = stats[CC + cb + 1] * inv_n - m1 * m1;
            const float v2 = stats[CC + cb + 2] * inv_n - m2 * m2;
            const float v3 = stats[CC + cb + 3] * inv_n - m3 * m3;
            sc.x = gamma[cb + 0] * rsqrtf(v0 + BN_EPS);
            sc.y = gamma[cb + 1] * rsqrtf(v1 + BN_EPS);
            sc.z = gamma[cb + 2] * rsqrtf(v2 + BN_EPS);
            sc.w = gamma[cb + 3] * rsqrtf(v3 + BN_EPS);
            bi.x = beta[cb + 0] - m0 * sc.x;
            bi.y = beta[cb + 1] - m1 * sc.y;
            bi.z = beta[cb + 2] - m2 * sc.z;
            bi.w = beta[cb + 3] - m3 * sc.w;
        }

        const uint2* cbf = reinterpret_cast<const uint2*>(conv_bf);
        for (int nb = blockIdx.x; nb < NN / 4; nb += gridDim.x) {
            const int i = (nb * 4 + g) * 48 + q;
            const uint2 u = cbf[i];
            float4 v;
            v.x = fmaf(__uint_as_float(u.x << 16),         sc.x, bi.x);
            v.y = fmaf(__uint_as_float(u.x & 0xFFFF0000u), sc.y, bi.y);
            v.z = fmaf(__uint_as_float(u.y << 16),         sc.z, bi.z);
            v.w = fmaf(__uint_as_float(u.y & 0xFFFF0000u), sc.w, bi.w);
            reinterpret_cast<float4*>(out)[i] = v;
        }
    }
}

// ---------------------------------------------------------------------------
// Fallback tier (ws too small or cooperative launch unavailable):
// R5's proven 3-kernel fp32 path.
// ---------------------------------------------------------------------------
__global__ __launch_bounds__(CC) void conv_bn_partial_f32(
    const float* __restrict__ data,
    const int*   __restrict__ neigh,
    const float* __restrict__ weight,
    float*       __restrict__ conv_out,
    float*       __restrict__ ch_sum,
    float*       __restrict__ ch_sumsq)
{
    const int c = threadIdx.x;
    const int base = blockIdx.x * NB;
    float w[KK];
#pragma unroll
    for (int k = 0; k < KK; ++k) w[k] = weight[k * CC + c];
    float s = 0.f, ss = 0.f;
    for (int n = 0; n < NB; ++n) {
        const int node = base + n;
        const int* nrow = neigh + node * KK;
        float acc = 0.f;
#pragma unroll
        for (int k = 0; k < KK; ++k)
            acc = fmaf(data[nrow[k] * CC + c], w[k], acc);
        conv_out[node * CC + c] = acc;
        s += acc; ss += acc * acc;
    }
    atomicAdd(&ch_sum[c], s);
    atomicAdd(&ch_sumsq[c], ss);
}

__global__ __launch_bounds__(192) void bn_apply_f32_fused(
    float* __restrict__ out,
    const float* __restrict__ ch_sum,
    const float* __restrict__ ch_sumsq,
    const float* __restrict__ gamma,
    const float* __restrict__ beta)
{
    const int t = threadIdx.x;
    const int g = t / 48;
    const int q = t - g * 48;
    const int cb = q * 4;
    const float inv_n = 1.0f / (float)NN;
    float4 sc, bi;
    const float m0 = ch_sum[cb+0]*inv_n, m1 = ch_sum[cb+1]*inv_n;
    const float m2 = ch_sum[cb+2]*inv_n, m3 = ch_sum[cb+3]*inv_n;
    sc.x = gamma[cb+0]*rsqrtf(ch_sumsq[cb+0]*inv_n - m0*m0 + BN_EPS);
    sc.y = gamma[cb+1]*rsqrtf(ch_sumsq[cb+1]*inv_n - m1*m1 + BN_EPS);
    sc.z = gamma[cb+2]*rsqrtf(ch_sumsq[cb+2]*inv_n - m2*m2 + BN_EPS);
    sc.w = gamma[cb+3]*rsqrtf(ch_sumsq[cb+3]*inv_n - m3*m3 + BN_EPS);
    bi.x = beta[cb+0] - m0*sc.x; bi.y = beta[cb+1] - m1*sc.y;
    bi.z = beta[cb+2] - m2*sc.z; bi.w = beta[cb+3] - m3*sc.w;
    for (int nb = blockIdx.x; nb < NN / 4; nb += gridDim.x) {
        const int i = (nb * 4 + g) * 48 + q;
        float4 v = reinterpret_cast<float4*>(out)[i];
        v.x = fmaf(v.x, sc.x, bi.x); v.y = fmaf(v.y, sc.y, bi.y);
        v.z = fmaf(v.z, sc.z, bi.z); v.w = fmaf(v.w, sc.w, bi.w);
        reinterpret_cast<float4*>(out)[i] = v;
    }
}

extern "C" void kernel_launch(void* const* d_in, const int* in_sizes, int n_in,
                              void* d_out, int out_size, void* d_ws, size_t ws_size,
                              hipStream_t stream) {
    const float* data   = (const float*)d_in[0];
    const int*   neigh  = (const int*)  d_in[1];
    const float* weight = (const float*)d_in[2];
    const float* gamma  = (const float*)d_in[3];
    const float* beta   = (const float*)d_in[4];
    float* out = (float*)d_out;

    // ws: stats 2*CC floats (padded to 4096 B) | data_bf 50.3 MB | conv_bf 50.3 MB
    float* stats = (float*)d_ws;
    unsigned short* data_bf = (unsigned short*)((char*)d_ws + 4096);
    const size_t stage_bytes = (size_t)NN * CC * sizeof(unsigned short);
    unsigned short* conv_bf =
        (unsigned short*)((char*)d_ws + 4096 + stage_bytes);
    const size_t need_full = 4096 + 2 * stage_bytes;

    bool coop_ok = (ws_size >= need_full);
    int grid_blocks = 0;
    if (coop_ok) {
        int blocks_per_cu = 0;
        hipError_t e = hipOccupancyMaxActiveBlocksPerMultiprocessor(
            &blocks_per_cu, (const void*)fused_all, 192, 0);
        if (e != hipSuccess || blocks_per_cu < 1) coop_ok = false;
        else grid_blocks = blocks_per_cu * 256;       // 256 CUs on MI355X
        if (grid_blocks > NN / NB) grid_blocks = NN / NB;
    }

    if (coop_ok) {
        void* args[] = {
            (void*)&data, (void*)&neigh, (void*)&weight,
            (void*)&gamma, (void*)&beta,
            (void*)&data_bf, (void*)&conv_bf, (void*)&stats, (void*)&out
        };
        hipError_t e = hipLaunchCooperativeKernel(
            (const void*)fused_all, dim3(grid_blocks), dim3(192),
            args, 0, stream);
        if (e == hipSuccess) return;
        // fall through to fallback on failure
    }

    // Fallback: fp32 3-dispatch path (no bf16 staging needed).
    float* ch_sum   = stats;
    float* ch_sumsq = stats + CC;
    hipMemsetAsync(stats, 0, 2 * CC * sizeof(float), stream);
    conv_bn_partial_f32<<<NN / NB, CC, 0, stream>>>(
        data, neigh, weight, out, ch_sum, ch_sumsq);
    bn_apply_f32_fused<<<8192, 192, 0, stream>>>(
        out, ch_sum, ch_sumsq, gamma, beta);
}